// Round 11
// baseline (107.461 us; speedup 1.0000x reference)
//
#include <hip/hip_runtime.h>
#include <cstdint>
#include <cstddef>

// CNLinkPredictor on MI355X — round 11: XIJ branch moved into k_prep
// (rides along with the BW-bound bitmask), edge chain loses 2 phases.
//   k_prep (2352 blocks, 256 thr):
//     blocks 0..47    : 6 weights -> frag-major split planes
//     blocks 48..303  : XIJ = relu((xi*xj)@xij_w+b) -> global f32 (weights
//                       read directly from global fp32 in frag pattern)
//     blocks 304..2351: adj -> bitmask (ballot, coalesced 256B segments)
//   k_edge_mega (256 blocks, 1024 thr): per 32-edge block:
//     scan bits[i]&bits[j] -> instance list; on-demand H chunks (xlin L1 ->
//     L2 + x resid -> atomicAdd XCN f32 LDS); XCN -> planes; T2 -> z(beta,
//     XIJ from global) -> L1 -> gemv.
//
// Layer math: split-bf16 (hi+lo, 3 MFMAs HH+HL+LH), mfma_f32_16x16x32_bf16.
// Edge: 16 waves, wave = 32 rows x 16 cols (nf=wq), 48 MFMA/layer/wave.
// LDS planes [32][256], chunk-XOR swizzle (c8 ^= row&7) -> conflict-free
// ds_read_b128. Weights frag-major in global (L2-resident), 16B/lane/frag.

#define C_DIM   256
#define N_NODES 8192
#define E_EDGES 8192

typedef short bf16x8 __attribute__((ext_vector_type(8)));
typedef float f32x4  __attribute__((ext_vector_type(4)));

struct WPtrs { const float* p[6]; };

__device__ __forceinline__ unsigned short bf16_rne(float a) {
    unsigned u = __float_as_uint(a);
    u += 0x7FFFu + ((u >> 16) & 1u);
    return (unsigned short)(u >> 16);
}
__device__ __forceinline__ void split2(float v, short& h, short& l) {
    unsigned short hb = bf16_rne(v);
    h = (short)hb;
    l = (short)bf16_rne(v - __uint_as_float((unsigned)hb << 16));
}

// ---------------- prep: weights + XIJ + bitmask ----------------
__global__ __launch_bounds__(256) void k_prep(const float* __restrict__ adj,
                                              const float* __restrict__ x,
                                              const int* __restrict__ tar,
                                              unsigned long long* __restrict__ bits,
                                              WPtrs wp, short* __restrict__ WFH,
                                              short* __restrict__ WFL,
                                              const float* __restrict__ bxij,
                                              float* __restrict__ XIJF) {
    const int t = threadIdx.x;
    if (blockIdx.x < 48) {
        // ---- weight g, k-frag kf -> frag-major split planes ----
        __shared__ float tile[32][257];
        const int g  = blockIdx.x >> 3;
        const int kf = blockIdx.x & 7;
        const float* W = wp.p[g];
        #pragma unroll
        for (int p = 0; p < 8; ++p) {
            int s = t + (p << 8);
            int row = s >> 6, c4 = s & 63;
            float4 v = *(const float4*)&W[(size_t)(kf * 32 + row) * C_DIM + (c4 << 2)];
            tile[row][(c4 << 2) + 0] = v.x; tile[row][(c4 << 2) + 1] = v.y;
            tile[row][(c4 << 2) + 2] = v.z; tile[row][(c4 << 2) + 3] = v.w;
        }
        __syncthreads();
        #pragma unroll
        for (int p = 0; p < 4; ++p) {
            int s = t + (p << 8);
            int nf = s >> 6, lane = s & 63;
            int q = lane >> 4, fr = lane & 15;
            short h[8], l[8];
            #pragma unroll
            for (int e = 0; e < 8; ++e)
                split2(tile[q * 8 + e][nf * 16 + fr], h[e], l[e]);
            int dst = (g << 16) + (((kf * 16 + nf) << 6) + lane) * 8;
            *(short4*)&WFH[dst]     = make_short4(h[0], h[1], h[2], h[3]);
            *(short4*)&WFH[dst + 4] = make_short4(h[4], h[5], h[6], h[7]);
            *(short4*)&WFL[dst]     = make_short4(l[0], l[1], l[2], l[3]);
            *(short4*)&WFL[dst + 4] = make_short4(l[4], l[5], l[6], l[7]);
        }
    } else if (blockIdx.x < 304) {
        // ---- XIJ block: 32 edges, 4 waves, weights direct from global ----
        __shared__ short XH[32][C_DIM], XL[32][C_DIM];
        __shared__ int   eij2[32][2];
        const int e0 = ((int)blockIdx.x - 48) << 5;
        if (t < 32) {
            eij2[t][0] = tar[e0 + t];
            eij2[t][1] = tar[E_EDGES + e0 + t];
        }
        __syncthreads();
        #pragma unroll
        for (int p = 0; p < 4; ++p) {
            int idx = (p << 8) + t;               // 1024 (r,c8) slots
            int r = idx >> 5, c = (idx & 31) << 3;
            float4 a0 = *(const float4*)&x[(size_t)eij2[r][0] * C_DIM + c];
            float4 a1 = *(const float4*)&x[(size_t)eij2[r][0] * C_DIM + c + 4];
            float4 b0 = *(const float4*)&x[(size_t)eij2[r][1] * C_DIM + c];
            float4 b1 = *(const float4*)&x[(size_t)eij2[r][1] * C_DIM + c + 4];
            float v[8] = {a0.x * b0.x, a0.y * b0.y, a0.z * b0.z, a0.w * b0.w,
                          a1.x * b1.x, a1.y * b1.y, a1.z * b1.z, a1.w * b1.w};
            short h[8], l[8];
            #pragma unroll
            for (int e = 0; e < 8; ++e) split2(v[e], h[e], l[e]);
            int cw = (((c >> 3) ^ (r & 7)) << 3);
            *(short4*)&XH[r][cw]     = make_short4(h[0], h[1], h[2], h[3]);
            *(short4*)&XH[r][cw + 4] = make_short4(h[4], h[5], h[6], h[7]);
            *(short4*)&XL[r][cw]     = make_short4(l[0], l[1], l[2], l[3]);
            *(short4*)&XL[r][cw + 4] = make_short4(l[4], l[5], l[6], l[7]);
        }
        __syncthreads();
        const int lane = t & 63, w = t >> 6;      // 4 waves
        const int fr = lane & 15, q = lane >> 4;
        const float* Wg = wp.p[2];                 // xij_w
        f32x4 acc[2][4];
        #pragma unroll
        for (int mf = 0; mf < 2; ++mf)
            #pragma unroll
            for (int nfi = 0; nfi < 4; ++nfi)
                #pragma unroll
                for (int r = 0; r < 4; ++r) acc[mf][nfi][r] = 0.f;
        for (int kf = 0; kf < 8; ++kf) {
            bf16x8 aH[2], aL[2];
            #pragma unroll
            for (int mf = 0; mf < 2; ++mf) {
                const int row = mf * 16 + fr;
                const int cc = (((kf << 2) + q) ^ (row & 7)) << 3;
                aH[mf] = *(const bf16x8*)&XH[row][cc];
                aL[mf] = *(const bf16x8*)&XL[row][cc];
            }
            #pragma unroll
            for (int nfi = 0; nfi < 4; ++nfi) {
                const int nf = (w << 2) + nfi;
                bf16x8 bH, bL;
                #pragma unroll
                for (int e = 0; e < 8; ++e) {
                    float wv = Wg[(size_t)(kf * 32 + q * 8 + e) * C_DIM + (nf << 4) + fr];
                    short h, l;
                    split2(wv, h, l);
                    bH[e] = h; bL[e] = l;
                }
                #pragma unroll
                for (int mf = 0; mf < 2; ++mf) {
                    acc[mf][nfi] = __builtin_amdgcn_mfma_f32_16x16x32_bf16(aH[mf], bH, acc[mf][nfi], 0, 0, 0);
                    acc[mf][nfi] = __builtin_amdgcn_mfma_f32_16x16x32_bf16(aH[mf], bL, acc[mf][nfi], 0, 0, 0);
                    acc[mf][nfi] = __builtin_amdgcn_mfma_f32_16x16x32_bf16(aL[mf], bH, acc[mf][nfi], 0, 0, 0);
                }
            }
        }
        #pragma unroll
        for (int nfi = 0; nfi < 4; ++nfi) {
            const int col = ((w << 2) + nfi) * 16 + fr;
            const float bb = bxij[col];
            #pragma unroll
            for (int mf = 0; mf < 2; ++mf)
                #pragma unroll
                for (int r = 0; r < 4; ++r) {
                    const int row = mf * 16 + q * 4 + r;
                    XIJF[(size_t)(e0 + row) * C_DIM + col] =
                        fmaxf(acc[mf][nfi][r] + bb, 0.f);
                }
        }
    } else {
        // ---- bitmask: ballot, one 256B coalesced segment per load ----
        const int TOTALW = N_NODES * N_NODES / 64;        // 1M words
        const int gw   = ((int)blockIdx.x - 304) * 4 + (t >> 6);   // 0..8191
        const int lane = t & 63;
        const int NW   = 2048 * 4;
        for (int w = gw << 3; w < TOTALW; w += NW << 3) {
            float v[8];
            #pragma unroll
            for (int r = 0; r < 8; ++r)
                v[r] = adj[((size_t)(w + r) << 6) + lane];
            unsigned long long m[8];
            #pragma unroll
            for (int r = 0; r < 8; ++r)
                m[r] = __ballot(v[r] > 0.5f);
            if (lane == 0) {
                #pragma unroll
                for (int r = 0; r < 4; ++r) {
                    ulonglong2 u2; u2.x = m[2 * r]; u2.y = m[2 * r + 1];
                    *(ulonglong2*)&bits[w + 2 * r] = u2;
                }
            }
        }
    }
}

// ---- split-bf16 layer core, 16 waves: wave wq owns nf=wq (cols wq*16..+15) --
// MODE 0: split -> POH/POL
// MODE 1: v = v*beta + XIJF[e0+row][col], split -> POH/POL
// MODE 4: gemv: out32[row] += sum_col v*w2[col]
template<int MODE>
__device__ __forceinline__ void layer_sb(
    const short (*INH)[C_DIM], const short (*INL)[C_DIM],
    const short* __restrict__ WH, const short* __restrict__ WL,
    const float* __restrict__ bias,
    short (*POH)[C_DIM], short (*POL)[C_DIM],
    const float* __restrict__ xijg, int e0,
    float beta, const float* __restrict__ w2, float* __restrict__ out32)
{
    const int t = threadIdx.x, lane = t & 63, wq = t >> 6;   // 16 waves
    const int fr = lane & 15, q = lane >> 4;
    f32x4 acc[2];
    #pragma unroll
    for (int i = 0; i < 2; ++i)
        #pragma unroll
        for (int r = 0; r < 4; ++r) acc[i][r] = 0.f;

    #pragma unroll 2
    for (int kf = 0; kf < 8; ++kf) {
        bf16x8 aH[2], aL[2];
        #pragma unroll
        for (int mf = 0; mf < 2; ++mf) {
            const int row = mf * 16 + fr;
            const int cc = (((kf << 2) + q) ^ (row & 7)) << 3;
            aH[mf] = *(const bf16x8*)&INH[row][cc];
            aL[mf] = *(const bf16x8*)&INL[row][cc];
        }
        const int wo = (((kf << 4) + wq) * 64 + lane) * 8;
        bf16x8 bH = *(const bf16x8*)&WH[wo];
        bf16x8 bL = *(const bf16x8*)&WL[wo];
        #pragma unroll
        for (int mf = 0; mf < 2; ++mf) {
            acc[mf] = __builtin_amdgcn_mfma_f32_16x16x32_bf16(aH[mf], bH, acc[mf], 0, 0, 0);
            acc[mf] = __builtin_amdgcn_mfma_f32_16x16x32_bf16(aH[mf], bL, acc[mf], 0, 0, 0);
            acc[mf] = __builtin_amdgcn_mfma_f32_16x16x32_bf16(aL[mf], bH, acc[mf], 0, 0, 0);
        }
    }

    const int col = (wq << 4) + fr;
    const float bb = bias[col];
    float gs[2][4];
    if (MODE == 4) {
        #pragma unroll
        for (int mf = 0; mf < 2; ++mf)
            #pragma unroll
            for (int r = 0; r < 4; ++r) gs[mf][r] = 0.f;
    }
    const float w2c = (MODE == 4) ? w2[col] : 0.f;
    #pragma unroll
    for (int mf = 0; mf < 2; ++mf)
        #pragma unroll
        for (int r = 0; r < 4; ++r) {
            const int row = mf * 16 + q * 4 + r;
            float v = fmaxf(acc[mf][r] + bb, 0.f);
            if (MODE == 0 || MODE == 1) {
                if (MODE == 1) v = v * beta + xijg[(size_t)(e0 + row) * C_DIM + col];
                short h, l;
                split2(v, h, l);
                const int cw = (((col >> 3) ^ (row & 7)) << 3) + (col & 7);
                POH[row][cw] = h;
                POL[row][cw] = l;
            } else {
                gs[mf][r] += v * w2c;
            }
        }
    if (MODE == 4) {
        #pragma unroll
        for (int mf = 0; mf < 2; ++mf)
            #pragma unroll
            for (int r = 0; r < 4; ++r) {
                float s = gs[mf][r];
                s += __shfl_xor(s, 1); s += __shfl_xor(s, 2);
                s += __shfl_xor(s, 4); s += __shfl_xor(s, 8);
                if (fr == 0) atomicAdd(&out32[mf * 16 + q * 4 + r], s);
            }
    }
}

// ---- chunk layer-2: Hrow = relu(IN @ W + b) + x[k]; XCN[e] += Hrow ----
__device__ __forceinline__ void layer_h2(
    const short (*INH)[C_DIM], const short (*INL)[C_DIM],
    const short* __restrict__ WH, const short* __restrict__ WL,
    const float* __restrict__ bias, const int* __restrict__ inst, int nrows,
    const float* __restrict__ xsrc, float (*XCN)[C_DIM])
{
    const int t = threadIdx.x, lane = t & 63, wq = t >> 6;
    const int fr = lane & 15, q = lane >> 4;
    f32x4 acc[2];
    #pragma unroll
    for (int i = 0; i < 2; ++i)
        #pragma unroll
        for (int r = 0; r < 4; ++r) acc[i][r] = 0.f;

    #pragma unroll 2
    for (int kf = 0; kf < 8; ++kf) {
        bf16x8 aH[2], aL[2];
        #pragma unroll
        for (int mf = 0; mf < 2; ++mf) {
            const int row = mf * 16 + fr;
            const int cc = (((kf << 2) + q) ^ (row & 7)) << 3;
            aH[mf] = *(const bf16x8*)&INH[row][cc];
            aL[mf] = *(const bf16x8*)&INL[row][cc];
        }
        const int wo = (((kf << 4) + wq) * 64 + lane) * 8;
        bf16x8 bH = *(const bf16x8*)&WH[wo];
        bf16x8 bL = *(const bf16x8*)&WL[wo];
        #pragma unroll
        for (int mf = 0; mf < 2; ++mf) {
            acc[mf] = __builtin_amdgcn_mfma_f32_16x16x32_bf16(aH[mf], bH, acc[mf], 0, 0, 0);
            acc[mf] = __builtin_amdgcn_mfma_f32_16x16x32_bf16(aH[mf], bL, acc[mf], 0, 0, 0);
            acc[mf] = __builtin_amdgcn_mfma_f32_16x16x32_bf16(aL[mf], bH, acc[mf], 0, 0, 0);
        }
    }
    const int col = (wq << 4) + fr;
    const float bb = bias[col];
    #pragma unroll
    for (int mf = 0; mf < 2; ++mf)
        #pragma unroll
        for (int r = 0; r < 4; ++r) {
            const int row = mf * 16 + q * 4 + r;
            if (row < nrows) {
                const int pk = inst[row];
                const int e  = pk >> 16;
                const int k  = pk & 0xffff;
                float v = fmaxf(acc[mf][r] + bb, 0.f) + xsrc[(size_t)k * C_DIM + col];
                atomicAdd(&XCN[e][col], v);
            }
        }
}

// ---------------- edge mega-kernel: 1024 threads ----------------
__global__ __launch_bounds__(1024, 1) void k_edge_mega(
    const unsigned long long* __restrict__ bits, const float* __restrict__ x,
    const int* __restrict__ tar,
    const short* __restrict__ WFH, const short* __restrict__ WFL,
    const float* __restrict__ b1x, const float* __restrict__ b2x,
    const float* __restrict__ bcn1, const float* __restrict__ bcn2,
    const float* __restrict__ blin1, const float* __restrict__ betap,
    const float* __restrict__ xijg, const float* __restrict__ w2,
    const float* __restrict__ b2o, float* __restrict__ out)
{
    __shared__ short AH[32][C_DIM], AL[32][C_DIM];   // plane A (32 KB)
    __shared__ short BH[32][C_DIM], BL[32][C_DIM];   // plane B (32 KB)
    __shared__ float CF[32][C_DIM];                  // f32 XCN accumulator (32 KB)
    __shared__ int   eij2[32][2];
    __shared__ int   inst[1024];
    __shared__ int   cntot;
    __shared__ float out32[32];
    const int e0 = blockIdx.x << 5;
    const int t = threadIdx.x;
    if (t < 32) {
        eij2[t][0] = tar[e0 + t];
        eij2[t][1] = tar[E_EDGES + e0 + t];
        out32[t] = 0.f;
    }
    if (t == 0) cntot = 0;
    __syncthreads();
    // zero XCN accumulator
    #pragma unroll
    for (int p = 0; p < 8; ++p) {
        int idx = (p << 10) + t;
        CF[idx >> 8][idx & 255] = 0.f;
    }
    // CN bit-scan: 32 threads/edge, 4 u64 words each
    {
        const int le = t >> 5, sub = t & 31;
        const size_t bi = (size_t)eij2[le][0] * 128;
        const size_t bj = (size_t)eij2[le][1] * 128;
        #pragma unroll
        for (int w4 = 0; w4 < 4; ++w4) {
            const int w = (sub << 2) + w4;
            unsigned long long m = bits[bi + w] & bits[bj + w];
            while (m) {
                int b = __builtin_ctzll(m);
                int slot = atomicAdd(&cntot, 1);
                if (slot < 1024) inst[slot] = (le << 16) | ((w << 6) + b);
                m &= m - 1;
            }
        }
    }
    __syncthreads();
    const int ctot = min(cntot, 1024);
    // ---- on-demand H: chunks of 32 CN instances ----
    for (int c0 = 0; c0 < ctot; c0 += 32) {
        const int nrows = min(32, ctot - c0);
        #pragma unroll
        for (int p = 0; p < 8; ++p) {
            int idx = (p << 10) + t;
            int r = idx >> 8, c = idx & 255;
            float v = 0.f;
            if (r < nrows) {
                int k = inst[c0 + r] & 0xffff;
                v = x[(size_t)k * C_DIM + c];
            }
            short h, l;
            split2(v, h, l);
            int cw = (((c >> 3) ^ (r & 7)) << 3) + (c & 7);
            AH[r][cw] = h;
            AL[r][cw] = l;
        }
        __syncthreads();
        layer_sb<0>(AH, AL, WFH + 0 * 65536, WFL + 0 * 65536, b1x,
                    BH, BL, nullptr, 0, 0.f, nullptr, nullptr);
        __syncthreads();
        layer_h2(BH, BL, WFH + 1 * 65536, WFL + 1 * 65536, b2x,
                 inst + c0, nrows, x, CF);
        __syncthreads();
    }
    // ---- split XCN -> B planes ----
    #pragma unroll
    for (int p = 0; p < 8; ++p) {
        int idx = (p << 10) + t;
        int r = idx >> 8, c = idx & 255;
        short h, l;
        split2(CF[r][c], h, l);
        int cw = (((c >> 3) ^ (r & 7)) << 3) + (c & 7);
        BH[r][cw] = h;
        BL[r][cw] = l;
    }
    __syncthreads();
    const float beta = betap[0];
    // T2 = relu(xcn @ xcn_w1 + b) -> A
    layer_sb<0>(BH, BL, WFH + 3 * 65536, WFL + 3 * 65536, bcn1,
                AH, AL, nullptr, 0, 0.f, nullptr, nullptr);
    __syncthreads();
    // z = relu(T2 @ xcn_w2 + b)*beta + XIJ(global) -> B
    layer_sb<1>(AH, AL, WFH + 4 * 65536, WFL + 4 * 65536, bcn2,
                BH, BL, xijg, e0, beta, nullptr, nullptr);
    __syncthreads();
    // out = relu(z @ lin_w1 + b) @ w2  (gemv fused)
    layer_sb<4>(BH, BL, WFH + 5 * 65536, WFL + 5 * 65536, blin1,
                nullptr, nullptr, nullptr, 0, 0.f, w2, out32);
    __syncthreads();
    if (t < 32) out[e0 + t] = out32[t] + b2o[0];
}

extern "C" void kernel_launch(void* const* d_in, const int* in_sizes, int n_in,
                              void* d_out, int out_size, void* d_ws, size_t ws_size,
                              hipStream_t stream) {
    const float* x       = (const float*)d_in[0];
    const float* adj     = (const float*)d_in[1];
    const int*   tar_ei  = (const int*)  d_in[2];
    const float* xlin_w1 = (const float*)d_in[3];
    const float* xlin_b1 = (const float*)d_in[4];
    const float* xlin_w2 = (const float*)d_in[5];
    const float* xlin_b2 = (const float*)d_in[6];
    const float* xcn_w1  = (const float*)d_in[7];
    const float* xcn_b1  = (const float*)d_in[8];
    const float* xcn_w2  = (const float*)d_in[9];
    const float* xcn_b2  = (const float*)d_in[10];
    const float* xij_w   = (const float*)d_in[11];
    const float* xij_b   = (const float*)d_in[12];
    const float* lin_w1  = (const float*)d_in[13];
    const float* lin_b1  = (const float*)d_in[14];
    const float* lin_w2  = (const float*)d_in[15];
    const float* lin_b2  = (const float*)d_in[16];
    const float* beta    = (const float*)d_in[17];
    float* out = (float*)d_out;

    char* ws = (char*)d_ws;
    const size_t MB = 1024 * 1024;
    unsigned long long* bits = (unsigned long long*)(ws);       // 8 MB
    short* WFH  = (short*)(ws +  8 * MB);   // 768 KB
    short* WFL  = (short*)(ws +  9 * MB);   // 768 KB
    float* XIJF = (float*)(ws + 10 * MB);   // 8 MB

    WPtrs wp;
    wp.p[0] = xlin_w1; wp.p[1] = xlin_w2; wp.p[2] = xij_w;
    wp.p[3] = xcn_w1;  wp.p[4] = xcn_w2;  wp.p[5] = lin_w1;

    hipLaunchKernelGGL(k_prep, dim3(48 + 256 + 2048), dim3(256), 0, stream,
                       adj, x, tar_ei, bits, wp, WFH, WFL, xij_b, XIJF);
    hipLaunchKernelGGL(k_edge_mega, dim3(E_EDGES / 32), dim3(1024), 0, stream,
                       bits, x, tar_ei, WFH, WFL,
                       xlin_b1, xlin_b2, xcn_b1, xcn_b2, lin_b1,
                       beta, XIJF, lin_w2, lin_b2, out);
}

// Round 12
// 80.724 us; speedup vs baseline: 1.3312x; 1.3312x over previous
//
#include <hip/hip_runtime.h>
#include <cstdint>
#include <cstddef>

// CNLinkPredictor on MI355X — round 12: revert XIJ-in-prep (r11 regression:
// scalar weight-split in consumer = VALU-bound stragglers). Round-10 prep +
// restructured edge kernel: XIJ and XCN live in REGISTERS (same (row,col)
// ownership across layers), no CF plane, no LDS atomics, ~10 barriers.
//   k_prep (2096 blocks): 48 weight blocks -> frag-major split planes;
//                         2048 bitmask blocks (ballot, coalesced 256B).
//   k_edge_mega (256 blocks, 1024 thr, 16 waves): per 32-edge block:
//     P1 xij->B planes + CN bit-scan (merged, 1 barrier)
//     P2 XIJ layer: B -> registers (xijr[2][4])
//     P3 per chunk<=32 CN instances: stage x[k]->A; T1: A->B; H=relu(T1@w2)+x[k]
//        split->A rows; reduce: A rows -> xcnreg[8] per thread
//     P4 xcnreg -> A planes
//     P5 T2: A->B   P6 z: B->A (v*beta + xijr)   P7 gemv -> out
//
// Layer math: split-bf16 (hi+lo, 3 MFMAs HH+HL+LH), mfma_f32_16x16x32_bf16.
// 16 waves, wave = 32 rows x 16 cols (nf=wq), 48 MFMA/layer/wave. LDS planes
// [32][256] chunk-XOR swizzle (c8 ^= row&7) -> conflict-free ds_read_b128.
// Weights frag-major in global (L2-resident), one 16B load/lane/frag.

#define C_DIM   256
#define N_NODES 8192
#define E_EDGES 8192

typedef short bf16x8 __attribute__((ext_vector_type(8)));
typedef float f32x4  __attribute__((ext_vector_type(4)));

struct WPtrs { const float* p[6]; };

__device__ __forceinline__ unsigned short bf16_rne(float a) {
    unsigned u = __float_as_uint(a);
    u += 0x7FFFu + ((u >> 16) & 1u);
    return (unsigned short)(u >> 16);
}
__device__ __forceinline__ void split2(float v, short& h, short& l) {
    unsigned short hb = bf16_rne(v);
    h = (short)hb;
    l = (short)bf16_rne(v - __uint_as_float((unsigned)hb << 16));
}
__device__ __forceinline__ float bf2f(short h) {
    return __uint_as_float(((unsigned)(unsigned short)h) << 16);
}

// ---------------- prep: weights (blocks 0..47) + bitmask (blocks 48..) ------
__global__ __launch_bounds__(256) void k_prep(const float* __restrict__ adj,
                                              unsigned long long* __restrict__ bits,
                                              WPtrs wp, short* __restrict__ WFH,
                                              short* __restrict__ WFL) {
    const int t = threadIdx.x;
    if (blockIdx.x < 48) {
        __shared__ float tile[32][257];
        const int g  = blockIdx.x >> 3;
        const int kf = blockIdx.x & 7;
        const float* W = wp.p[g];
        #pragma unroll
        for (int p = 0; p < 8; ++p) {
            int s = t + (p << 8);
            int row = s >> 6, c4 = s & 63;
            float4 v = *(const float4*)&W[(size_t)(kf * 32 + row) * C_DIM + (c4 << 2)];
            tile[row][(c4 << 2) + 0] = v.x; tile[row][(c4 << 2) + 1] = v.y;
            tile[row][(c4 << 2) + 2] = v.z; tile[row][(c4 << 2) + 3] = v.w;
        }
        __syncthreads();
        #pragma unroll
        for (int p = 0; p < 4; ++p) {
            int s = t + (p << 8);
            int nf = s >> 6, lane = s & 63;
            int q = lane >> 4, fr = lane & 15;
            short h[8], l[8];
            #pragma unroll
            for (int e = 0; e < 8; ++e)
                split2(tile[q * 8 + e][nf * 16 + fr], h[e], l[e]);
            int dst = (g << 16) + (((kf * 16 + nf) << 6) + lane) * 8;
            *(short4*)&WFH[dst]     = make_short4(h[0], h[1], h[2], h[3]);
            *(short4*)&WFH[dst + 4] = make_short4(h[4], h[5], h[6], h[7]);
            *(short4*)&WFL[dst]     = make_short4(l[0], l[1], l[2], l[3]);
            *(short4*)&WFL[dst + 4] = make_short4(l[4], l[5], l[6], l[7]);
        }
    } else {
        const int TOTALW = N_NODES * N_NODES / 64;        // 1M words
        const int gw   = ((int)blockIdx.x - 48) * 4 + (t >> 6);   // 0..8191
        const int lane = t & 63;
        const int NW   = 2048 * 4;
        for (int w = gw << 3; w < TOTALW; w += NW << 3) {
            float v[8];
            #pragma unroll
            for (int r = 0; r < 8; ++r)
                v[r] = adj[((size_t)(w + r) << 6) + lane];
            unsigned long long m[8];
            #pragma unroll
            for (int r = 0; r < 8; ++r)
                m[r] = __ballot(v[r] > 0.5f);
            if (lane == 0) {
                #pragma unroll
                for (int r = 0; r < 4; ++r) {
                    ulonglong2 u2; u2.x = m[2 * r]; u2.y = m[2 * r + 1];
                    *(ulonglong2*)&bits[w + 2 * r] = u2;
                }
            }
        }
    }
}

// ---- split-bf16 layer core: acc[2] = IN(32x256) @ W-frags (nf=wq) ----
__device__ __forceinline__ void layer_core(
    const short (*INH)[C_DIM], const short (*INL)[C_DIM],
    const short* __restrict__ WH, const short* __restrict__ WL,
    f32x4 acc[2])
{
    const int t = threadIdx.x, lane = t & 63, wq = t >> 6;   // 16 waves
    const int fr = lane & 15, q = lane >> 4;
    #pragma unroll
    for (int i = 0; i < 2; ++i)
        #pragma unroll
        for (int r = 0; r < 4; ++r) acc[i][r] = 0.f;
    #pragma unroll 2
    for (int kf = 0; kf < 8; ++kf) {
        bf16x8 aH[2], aL[2];
        #pragma unroll
        for (int mf = 0; mf < 2; ++mf) {
            const int row = mf * 16 + fr;
            const int cc = (((kf << 2) + q) ^ (row & 7)) << 3;
            aH[mf] = *(const bf16x8*)&INH[row][cc];
            aL[mf] = *(const bf16x8*)&INL[row][cc];
        }
        const int wo = (((kf << 4) + wq) * 64 + lane) * 8;
        bf16x8 bH = *(const bf16x8*)&WH[wo];
        bf16x8 bL = *(const bf16x8*)&WL[wo];
        #pragma unroll
        for (int mf = 0; mf < 2; ++mf) {
            acc[mf] = __builtin_amdgcn_mfma_f32_16x16x32_bf16(aH[mf], bH, acc[mf], 0, 0, 0);
            acc[mf] = __builtin_amdgcn_mfma_f32_16x16x32_bf16(aH[mf], bL, acc[mf], 0, 0, 0);
            acc[mf] = __builtin_amdgcn_mfma_f32_16x16x32_bf16(aL[mf], bH, acc[mf], 0, 0, 0);
        }
    }
}

// ---------------- edge mega-kernel: 1024 threads, 16 waves ----------------
__global__ __launch_bounds__(1024, 1) void k_edge_mega(
    const unsigned long long* __restrict__ bits, const float* __restrict__ x,
    const int* __restrict__ tar,
    const short* __restrict__ WFH, const short* __restrict__ WFL,
    const float* __restrict__ b1x, const float* __restrict__ b2x,
    const float* __restrict__ bxij, const float* __restrict__ bcn1,
    const float* __restrict__ bcn2, const float* __restrict__ blin1,
    const float* __restrict__ betap, const float* __restrict__ w2,
    const float* __restrict__ b2o, float* __restrict__ out)
{
    __shared__ short AH[32][C_DIM], AL[32][C_DIM];   // plane A (32 KB)
    __shared__ short BH[32][C_DIM], BL[32][C_DIM];   // plane B (32 KB)
    __shared__ int   eij2[32][2];
    __shared__ int   inst[1024];
    __shared__ int   cntot;
    __shared__ float out32[32];
    const int e0 = blockIdx.x << 5;
    const int t = threadIdx.x;
    const int lane = t & 63, wq = t >> 6;
    const int fr = lane & 15, q = lane >> 4;
    const int et = t >> 5;                // owned edge for xcn regs
    const int c8 = (t & 31) << 3;         // owned 8-col group

    if (t < 32) {
        eij2[t][0] = tar[e0 + t];
        eij2[t][1] = tar[E_EDGES + e0 + t];
        out32[t] = 0.f;
    }
    if (t == 0) cntot = 0;
    __syncthreads();

    // ---- P1: xij -> B planes  +  CN bit-scan (merged) ----
    #pragma unroll
    for (int p = 0; p < 8; ++p) {
        int idx = (p << 10) + t;
        int e = idx >> 8, c = idx & 255;
        float v = x[(size_t)eij2[e][0] * C_DIM + c] * x[(size_t)eij2[e][1] * C_DIM + c];
        short h, l;
        split2(v, h, l);
        int cw = (((c >> 3) ^ (e & 7)) << 3) + (c & 7);
        BH[e][cw] = h;
        BL[e][cw] = l;
    }
    {
        const int le = t >> 5, sub = t & 31;
        const size_t bi = (size_t)eij2[le][0] * 128;
        const size_t bj = (size_t)eij2[le][1] * 128;
        #pragma unroll
        for (int w4 = 0; w4 < 4; ++w4) {
            const int w = (sub << 2) + w4;
            unsigned long long m = bits[bi + w] & bits[bj + w];
            while (m) {
                int b = __builtin_ctzll(m);
                int slot = atomicAdd(&cntot, 1);
                if (slot < 1024) inst[slot] = (le << 16) | ((w << 6) + b);
                m &= m - 1;
            }
        }
    }
    __syncthreads();

    // ---- P2: XIJ layer B -> registers ----
    float xijr[2][4];
    {
        f32x4 acc[2];
        layer_core(BH, BL, WFH + 2 * 65536, WFL + 2 * 65536, acc);
        const int col = (wq << 4) + fr;
        const float bb = bxij[col];
        #pragma unroll
        for (int mf = 0; mf < 2; ++mf)
            #pragma unroll
            for (int r = 0; r < 4; ++r)
                xijr[mf][r] = fmaxf(acc[mf][r] + bb, 0.f);
    }

    // ---- P3: on-demand H chunks -> xcnreg ----
    float xcnreg[8];
    #pragma unroll
    for (int u = 0; u < 8; ++u) xcnreg[u] = 0.f;
    const int ctot = min(cntot, 1024);
    for (int c0 = 0; c0 < ctot; c0 += 32) {
        const int nrows = min(32, ctot - c0);
        // stage x[k] -> A
        #pragma unroll
        for (int p = 0; p < 8; ++p) {
            int idx = (p << 10) + t;
            int r = idx >> 8, c = idx & 255;
            float v = 0.f;
            if (r < nrows) {
                int k = inst[c0 + r] & 0xffff;
                v = x[(size_t)k * C_DIM + c];
            }
            short h, l;
            split2(v, h, l);
            int cw = (((c >> 3) ^ (r & 7)) << 3) + (c & 7);
            AH[r][cw] = h;
            AL[r][cw] = l;
        }
        __syncthreads();
        // T1 = relu(xk @ xlin_w1 + b1) : A -> B
        {
            f32x4 acc[2];
            layer_core(AH, AL, WFH + 0 * 65536, WFL + 0 * 65536, acc);
            const int col = (wq << 4) + fr;
            const float bb = b1x[col];
            #pragma unroll
            for (int mf = 0; mf < 2; ++mf)
                #pragma unroll
                for (int r = 0; r < 4; ++r) {
                    const int row = mf * 16 + q * 4 + r;
                    float v = fmaxf(acc[mf][r] + bb, 0.f);
                    short h, l;
                    split2(v, h, l);
                    const int cw = (((col >> 3) ^ (row & 7)) << 3) + (col & 7);
                    BH[row][cw] = h;
                    BL[row][cw] = l;
                }
        }
        __syncthreads();
        // H = relu(T1 @ xlin_w2 + b2) + x[k] : B -> A (split rows)
        {
            f32x4 acc[2];
            layer_core(BH, BL, WFH + 1 * 65536, WFL + 1 * 65536, acc);
            const int col = (wq << 4) + fr;
            const float bb = b2x[col];
            #pragma unroll
            for (int mf = 0; mf < 2; ++mf)
                #pragma unroll
                for (int r = 0; r < 4; ++r) {
                    const int row = mf * 16 + q * 4 + r;
                    if (row < nrows) {
                        const int k = inst[c0 + row] & 0xffff;
                        float v = fmaxf(acc[mf][r] + bb, 0.f) +
                                  x[(size_t)k * C_DIM + col];
                        short h, l;
                        split2(v, h, l);
                        const int cw = (((col >> 3) ^ (row & 7)) << 3) + (col & 7);
                        AH[row][cw] = h;
                        AL[row][cw] = l;
                    }
                }
        }
        __syncthreads();
        // reduce: A instance rows -> xcnreg (thread owns edge et, cols c8..c8+7)
        for (int s = 0; s < nrows; ++s) {
            int pk = inst[c0 + s];
            if ((pk >> 16) == et) {
                const int cw = ((c8 >> 3) ^ (s & 7)) << 3;
                short4 h0 = *(const short4*)&AH[s][cw];
                short4 h1 = *(const short4*)&AH[s][cw + 4];
                short4 l0 = *(const short4*)&AL[s][cw];
                short4 l1 = *(const short4*)&AL[s][cw + 4];
                xcnreg[0] += bf2f(h0.x) + bf2f(l0.x);
                xcnreg[1] += bf2f(h0.y) + bf2f(l0.y);
                xcnreg[2] += bf2f(h0.z) + bf2f(l0.z);
                xcnreg[3] += bf2f(h0.w) + bf2f(l0.w);
                xcnreg[4] += bf2f(h1.x) + bf2f(l1.x);
                xcnreg[5] += bf2f(h1.y) + bf2f(l1.y);
                xcnreg[6] += bf2f(h1.z) + bf2f(l1.z);
                xcnreg[7] += bf2f(h1.w) + bf2f(l1.w);
            }
        }
        __syncthreads();
    }

    // ---- P4: xcnreg -> A planes ----
    {
        const int cwb = ((c8 >> 3) ^ (et & 7)) << 3;
        short h[8], l[8];
        #pragma unroll
        for (int u = 0; u < 8; ++u) split2(xcnreg[u], h[u], l[u]);
        *(short4*)&AH[et][cwb]     = make_short4(h[0], h[1], h[2], h[3]);
        *(short4*)&AH[et][cwb + 4] = make_short4(h[4], h[5], h[6], h[7]);
        *(short4*)&AL[et][cwb]     = make_short4(l[0], l[1], l[2], l[3]);
        *(short4*)&AL[et][cwb + 4] = make_short4(l[4], l[5], l[6], l[7]);
    }
    __syncthreads();

    const float beta = betap[0];
    // ---- P5: T2 = relu(xcn @ xcn_w1 + b) : A -> B ----
    {
        f32x4 acc[2];
        layer_core(AH, AL, WFH + 3 * 65536, WFL + 3 * 65536, acc);
        const int col = (wq << 4) + fr;
        const float bb = bcn1[col];
        #pragma unroll
        for (int mf = 0; mf < 2; ++mf)
            #pragma unroll
            for (int r = 0; r < 4; ++r) {
                const int row = mf * 16 + q * 4 + r;
                float v = fmaxf(acc[mf][r] + bb, 0.f);
                short h, l;
                split2(v, h, l);
                const int cw = (((col >> 3) ^ (row & 7)) << 3) + (col & 7);
                BH[row][cw] = h;
                BL[row][cw] = l;
            }
    }
    __syncthreads();
    // ---- P6: z = relu(T2 @ xcn_w2 + b)*beta + XIJ(regs) : B -> A ----
    {
        f32x4 acc[2];
        layer_core(BH, BL, WFH + 4 * 65536, WFL + 4 * 65536, acc);
        const int col = (wq << 4) + fr;
        const float bb = bcn2[col];
        #pragma unroll
        for (int mf = 0; mf < 2; ++mf)
            #pragma unroll
            for (int r = 0; r < 4; ++r) {
                const int row = mf * 16 + q * 4 + r;
                float v = fmaxf(acc[mf][r] + bb, 0.f) * beta + xijr[mf][r];
                short h, l;
                split2(v, h, l);
                const int cw = (((col >> 3) ^ (row & 7)) << 3) + (col & 7);
                AH[row][cw] = h;
                AL[row][cw] = l;
            }
    }
    __syncthreads();
    // ---- P7: out = relu(z @ lin_w1 + b) @ w2 (gemv fused) ----
    {
        f32x4 acc[2];
        layer_core(AH, AL, WFH + 5 * 65536, WFL + 5 * 65536, acc);
        const int col = (wq << 4) + fr;
        const float bb = blin1[col];
        const float w2c = w2[col];
        #pragma unroll
        for (int mf = 0; mf < 2; ++mf) {
            #pragma unroll
            for (int r = 0; r < 4; ++r) {
                float s = fmaxf(acc[mf][r] + bb, 0.f) * w2c;
                s += __shfl_xor(s, 1); s += __shfl_xor(s, 2);
                s += __shfl_xor(s, 4); s += __shfl_xor(s, 8);
                if (fr == 0) atomicAdd(&out32[mf * 16 + q * 4 + r], s);
            }
        }
    }
    __syncthreads();
    if (t < 32) out[e0 + t] = out32[t] + b2o[0];
}

extern "C" void kernel_launch(void* const* d_in, const int* in_sizes, int n_in,
                              void* d_out, int out_size, void* d_ws, size_t ws_size,
                              hipStream_t stream) {
    const float* x       = (const float*)d_in[0];
    const float* adj     = (const float*)d_in[1];
    const int*   tar_ei  = (const int*)  d_in[2];
    const float* xlin_w1 = (const float*)d_in[3];
    const float* xlin_b1 = (const float*)d_in[4];
    const float* xlin_w2 = (const float*)d_in[5];
    const float* xlin_b2 = (const float*)d_in[6];
    const float* xcn_w1  = (const float*)d_in[7];
    const float* xcn_b1  = (const float*)d_in[8];
    const float* xcn_w2  = (const float*)d_in[9];
    const float* xcn_b2  = (const float*)d_in[10];
    const float* xij_w   = (const float*)d_in[11];
    const float* xij_b   = (const float*)d_in[12];
    const float* lin_w1  = (const float*)d_in[13];
    const float* lin_b1  = (const float*)d_in[14];
    const float* lin_w2  = (const float*)d_in[15];
    const float* lin_b2  = (const float*)d_in[16];
    const float* beta    = (const float*)d_in[17];
    float* out = (float*)d_out;

    char* ws = (char*)d_ws;
    const size_t MB = 1024 * 1024;
    unsigned long long* bits = (unsigned long long*)(ws);       // 8 MB
    short* WFH  = (short*)(ws +  8 * MB);   // 768 KB
    short* WFL  = (short*)(ws +  9 * MB);   // 768 KB

    WPtrs wp;
    wp.p[0] = xlin_w1; wp.p[1] = xlin_w2; wp.p[2] = xij_w;
    wp.p[3] = xcn_w1;  wp.p[4] = xcn_w2;  wp.p[5] = lin_w1;

    hipLaunchKernelGGL(k_prep, dim3(48 + 2048), dim3(256), 0, stream,
                       adj, bits, wp, WFH, WFL);
    hipLaunchKernelGGL(k_edge_mega, dim3(E_EDGES / 32), dim3(1024), 0, stream,
                       bits, x, tar_ei, WFH, WFL,
                       xlin_b1, xlin_b2, xij_b, xcn_b1, xcn_b2, lin_b1,
                       beta, lin_w2, lin_b2, out);
}

// Round 13
// 79.156 us; speedup vs baseline: 1.3576x; 1.0198x over previous
//
#include <hip/hip_runtime.h>
#include <cstdint>
#include <cstddef>

// CNLinkPredictor on MI355X — round 13: bf16-hi-only WEIGHTS (activations
// stay split hi+lo). 2 MFMAs per frag pair (aH*bH + aL*bH) instead of 3.
// Halves per-layer weight L2 traffic (384->192 MB) and post-barrier load
// latency. Accuracy trade: weight quant err ~2^-9 -> predicted absmax 2-5e-3
// (threshold 9.77e-3). Structure otherwise = round 12 (best, 80.7 us):
//   k_prep (2096 blocks): 48 weight blocks -> frag-major split planes
//                         (still writes lo plane: 1-line revert path);
//                         2048 bitmask blocks (ballot, coalesced 256B).
//   k_edge_mega (256 blocks, 1024 thr, 16 waves): per 32-edge block:
//     P1 xij->B planes + CN bit-scan; P2 XIJ->regs; P3 on-demand H chunks
//     (T1, H=relu(T1@w2)+x[k], reduce->xcnreg); P4 xcnreg->A; P5 T2;
//     P6 z=relu*beta+xijr; P7 lin1+gemv -> out.
// LDS planes [32][256] chunk-XOR swizzle (c8 ^= row&7); weights frag-major
// in global (L2-resident), one 16B load/lane/frag (hi only in edge kernel).

#define C_DIM   256
#define N_NODES 8192
#define E_EDGES 8192

typedef short bf16x8 __attribute__((ext_vector_type(8)));
typedef float f32x4  __attribute__((ext_vector_type(4)));

struct WPtrs { const float* p[6]; };

__device__ __forceinline__ unsigned short bf16_rne(float a) {
    unsigned u = __float_as_uint(a);
    u += 0x7FFFu + ((u >> 16) & 1u);
    return (unsigned short)(u >> 16);
}
__device__ __forceinline__ void split2(float v, short& h, short& l) {
    unsigned short hb = bf16_rne(v);
    h = (short)hb;
    l = (short)bf16_rne(v - __uint_as_float((unsigned)hb << 16));
}
__device__ __forceinline__ float bf2f(short h) {
    return __uint_as_float(((unsigned)(unsigned short)h) << 16);
}

// ---------------- prep: weights (blocks 0..47) + bitmask (blocks 48..) ------
__global__ __launch_bounds__(256) void k_prep(const float* __restrict__ adj,
                                              unsigned long long* __restrict__ bits,
                                              WPtrs wp, short* __restrict__ WFH,
                                              short* __restrict__ WFL) {
    const int t = threadIdx.x;
    if (blockIdx.x < 48) {
        __shared__ float tile[32][257];
        const int g  = blockIdx.x >> 3;
        const int kf = blockIdx.x & 7;
        const float* W = wp.p[g];
        #pragma unroll
        for (int p = 0; p < 8; ++p) {
            int s = t + (p << 8);
            int row = s >> 6, c4 = s & 63;
            float4 v = *(const float4*)&W[(size_t)(kf * 32 + row) * C_DIM + (c4 << 2)];
            tile[row][(c4 << 2) + 0] = v.x; tile[row][(c4 << 2) + 1] = v.y;
            tile[row][(c4 << 2) + 2] = v.z; tile[row][(c4 << 2) + 3] = v.w;
        }
        __syncthreads();
        #pragma unroll
        for (int p = 0; p < 4; ++p) {
            int s = t + (p << 8);
            int nf = s >> 6, lane = s & 63;
            int q = lane >> 4, fr = lane & 15;
            short h[8], l[8];
            #pragma unroll
            for (int e = 0; e < 8; ++e)
                split2(tile[q * 8 + e][nf * 16 + fr], h[e], l[e]);
            int dst = (g << 16) + (((kf * 16 + nf) << 6) + lane) * 8;
            *(short4*)&WFH[dst]     = make_short4(h[0], h[1], h[2], h[3]);
            *(short4*)&WFH[dst + 4] = make_short4(h[4], h[5], h[6], h[7]);
            *(short4*)&WFL[dst]     = make_short4(l[0], l[1], l[2], l[3]);
            *(short4*)&WFL[dst + 4] = make_short4(l[4], l[5], l[6], l[7]);
        }
    } else {
        const int TOTALW = N_NODES * N_NODES / 64;        // 1M words
        const int gw   = ((int)blockIdx.x - 48) * 4 + (t >> 6);   // 0..8191
        const int lane = t & 63;
        const int NW   = 2048 * 4;
        for (int w = gw << 3; w < TOTALW; w += NW << 3) {
            float v[8];
            #pragma unroll
            for (int r = 0; r < 8; ++r)
                v[r] = adj[((size_t)(w + r) << 6) + lane];
            unsigned long long m[8];
            #pragma unroll
            for (int r = 0; r < 8; ++r)
                m[r] = __ballot(v[r] > 0.5f);
            if (lane == 0) {
                #pragma unroll
                for (int r = 0; r < 4; ++r) {
                    ulonglong2 u2; u2.x = m[2 * r]; u2.y = m[2 * r + 1];
                    *(ulonglong2*)&bits[w + 2 * r] = u2;
                }
            }
        }
    }
}

// ---- split-act x bf16-weight layer core: acc[2] = IN(32x256) @ Whi (nf=wq) --
__device__ __forceinline__ void layer_core(
    const short (*INH)[C_DIM], const short (*INL)[C_DIM],
    const short* __restrict__ WH, f32x4 acc[2])
{
    const int t = threadIdx.x, lane = t & 63, wq = t >> 6;   // 16 waves
    const int fr = lane & 15, q = lane >> 4;
    #pragma unroll
    for (int i = 0; i < 2; ++i)
        #pragma unroll
        for (int r = 0; r < 4; ++r) acc[i][r] = 0.f;
    #pragma unroll 2
    for (int kf = 0; kf < 8; ++kf) {
        bf16x8 aH[2], aL[2];
        #pragma unroll
        for (int mf = 0; mf < 2; ++mf) {
            const int row = mf * 16 + fr;
            const int cc = (((kf << 2) + q) ^ (row & 7)) << 3;
            aH[mf] = *(const bf16x8*)&INH[row][cc];
            aL[mf] = *(const bf16x8*)&INL[row][cc];
        }
        const int wo = (((kf << 4) + wq) * 64 + lane) * 8;
        bf16x8 bH = *(const bf16x8*)&WH[wo];
        #pragma unroll
        for (int mf = 0; mf < 2; ++mf) {
            acc[mf] = __builtin_amdgcn_mfma_f32_16x16x32_bf16(aH[mf], bH, acc[mf], 0, 0, 0);
            acc[mf] = __builtin_amdgcn_mfma_f32_16x16x32_bf16(aL[mf], bH, acc[mf], 0, 0, 0);
        }
    }
}

// ---------------- edge mega-kernel: 1024 threads, 16 waves ----------------
__global__ __launch_bounds__(1024, 1) void k_edge_mega(
    const unsigned long long* __restrict__ bits, const float* __restrict__ x,
    const int* __restrict__ tar,
    const short* __restrict__ WFH,
    const float* __restrict__ b1x, const float* __restrict__ b2x,
    const float* __restrict__ bxij, const float* __restrict__ bcn1,
    const float* __restrict__ bcn2, const float* __restrict__ blin1,
    const float* __restrict__ betap, const float* __restrict__ w2,
    const float* __restrict__ b2o, float* __restrict__ out)
{
    __shared__ short AH[32][C_DIM], AL[32][C_DIM];   // plane A (32 KB)
    __shared__ short BH[32][C_DIM], BL[32][C_DIM];   // plane B (32 KB)
    __shared__ int   eij2[32][2];
    __shared__ int   inst[1024];
    __shared__ int   cntot;
    __shared__ float out32[32];
    const int e0 = blockIdx.x << 5;
    const int t = threadIdx.x;
    const int lane = t & 63, wq = t >> 6;
    const int fr = lane & 15, q = lane >> 4;
    const int et = t >> 5;                // owned edge for xcn regs
    const int c8 = (t & 31) << 3;         // owned 8-col group

    if (t < 32) {
        eij2[t][0] = tar[e0 + t];
        eij2[t][1] = tar[E_EDGES + e0 + t];
        out32[t] = 0.f;
    }
    if (t == 0) cntot = 0;
    __syncthreads();

    // ---- P1: xij -> B planes  +  CN bit-scan (merged) ----
    #pragma unroll
    for (int p = 0; p < 8; ++p) {
        int idx = (p << 10) + t;
        int e = idx >> 8, c = idx & 255;
        float v = x[(size_t)eij2[e][0] * C_DIM + c] * x[(size_t)eij2[e][1] * C_DIM + c];
        short h, l;
        split2(v, h, l);
        int cw = (((c >> 3) ^ (e & 7)) << 3) + (c & 7);
        BH[e][cw] = h;
        BL[e][cw] = l;
    }
    {
        const int le = t >> 5, sub = t & 31;
        const size_t bi = (size_t)eij2[le][0] * 128;
        const size_t bj = (size_t)eij2[le][1] * 128;
        #pragma unroll
        for (int w4 = 0; w4 < 4; ++w4) {
            const int w = (sub << 2) + w4;
            unsigned long long m = bits[bi + w] & bits[bj + w];
            while (m) {
                int b = __builtin_ctzll(m);
                int slot = atomicAdd(&cntot, 1);
                if (slot < 1024) inst[slot] = (le << 16) | ((w << 6) + b);
                m &= m - 1;
            }
        }
    }
    __syncthreads();

    // ---- P2: XIJ layer B -> registers ----
    float xijr[2][4];
    {
        f32x4 acc[2];
        layer_core(BH, BL, WFH + 2 * 65536, acc);
        const int col = (wq << 4) + fr;
        const float bb = bxij[col];
        #pragma unroll
        for (int mf = 0; mf < 2; ++mf)
            #pragma unroll
            for (int r = 0; r < 4; ++r)
                xijr[mf][r] = fmaxf(acc[mf][r] + bb, 0.f);
    }

    // ---- P3: on-demand H chunks -> xcnreg ----
    float xcnreg[8];
    #pragma unroll
    for (int u = 0; u < 8; ++u) xcnreg[u] = 0.f;
    const int ctot = min(cntot, 1024);
    for (int c0 = 0; c0 < ctot; c0 += 32) {
        const int nrows = min(32, ctot - c0);
        // stage x[k] -> A
        #pragma unroll
        for (int p = 0; p < 8; ++p) {
            int idx = (p << 10) + t;
            int r = idx >> 8, c = idx & 255;
            float v = 0.f;
            if (r < nrows) {
                int k = inst[c0 + r] & 0xffff;
                v = x[(size_t)k * C_DIM + c];
            }
            short h, l;
            split2(v, h, l);
            int cw = (((c >> 3) ^ (r & 7)) << 3) + (c & 7);
            AH[r][cw] = h;
            AL[r][cw] = l;
        }
        __syncthreads();
        // T1 = relu(xk @ xlin_w1 + b1) : A -> B
        {
            f32x4 acc[2];
            layer_core(AH, AL, WFH + 0 * 65536, acc);
            const int col = (wq << 4) + fr;
            const float bb = b1x[col];
            #pragma unroll
            for (int mf = 0; mf < 2; ++mf)
                #pragma unroll
                for (int r = 0; r < 4; ++r) {
                    const int row = mf * 16 + q * 4 + r;
                    float v = fmaxf(acc[mf][r] + bb, 0.f);
                    short h, l;
                    split2(v, h, l);
                    const int cw = (((col >> 3) ^ (row & 7)) << 3) + (col & 7);
                    BH[row][cw] = h;
                    BL[row][cw] = l;
                }
        }
        __syncthreads();
        // H = relu(T1 @ xlin_w2 + b2) + x[k] : B -> A (split rows)
        {
            f32x4 acc[2];
            layer_core(BH, BL, WFH + 1 * 65536, acc);
            const int col = (wq << 4) + fr;
            const float bb = b2x[col];
            #pragma unroll
            for (int mf = 0; mf < 2; ++mf)
                #pragma unroll
                for (int r = 0; r < 4; ++r) {
                    const int row = mf * 16 + q * 4 + r;
                    if (row < nrows) {
                        const int k = inst[c0 + row] & 0xffff;
                        float v = fmaxf(acc[mf][r] + bb, 0.f) +
                                  x[(size_t)k * C_DIM + col];
                        short h, l;
                        split2(v, h, l);
                        const int cw = (((col >> 3) ^ (row & 7)) << 3) + (col & 7);
                        AH[row][cw] = h;
                        AL[row][cw] = l;
                    }
                }
        }
        __syncthreads();
        // reduce: A instance rows -> xcnreg (thread owns edge et, cols c8..c8+7)
        for (int s = 0; s < nrows; ++s) {
            int pk = inst[c0 + s];
            if ((pk >> 16) == et) {
                const int cw = ((c8 >> 3) ^ (s & 7)) << 3;
                short4 h0 = *(const short4*)&AH[s][cw];
                short4 h1 = *(const short4*)&AH[s][cw + 4];
                short4 l0 = *(const short4*)&AL[s][cw];
                short4 l1 = *(const short4*)&AL[s][cw + 4];
                xcnreg[0] += bf2f(h0.x) + bf2f(l0.x);
                xcnreg[1] += bf2f(h0.y) + bf2f(l0.y);
                xcnreg[2] += bf2f(h0.z) + bf2f(l0.z);
                xcnreg[3] += bf2f(h0.w) + bf2f(l0.w);
                xcnreg[4] += bf2f(h1.x) + bf2f(l1.x);
                xcnreg[5] += bf2f(h1.y) + bf2f(l1.y);
                xcnreg[6] += bf2f(h1.z) + bf2f(l1.z);
                xcnreg[7] += bf2f(h1.w) + bf2f(l1.w);
            }
        }
        __syncthreads();
    }

    // ---- P4: xcnreg -> A planes ----
    {
        const int cwb = ((c8 >> 3) ^ (et & 7)) << 3;
        short h[8], l[8];
        #pragma unroll
        for (int u = 0; u < 8; ++u) split2(xcnreg[u], h[u], l[u]);
        *(short4*)&AH[et][cwb]     = make_short4(h[0], h[1], h[2], h[3]);
        *(short4*)&AH[et][cwb + 4] = make_short4(h[4], h[5], h[6], h[7]);
        *(short4*)&AL[et][cwb]     = make_short4(l[0], l[1], l[2], l[3]);
        *(short4*)&AL[et][cwb + 4] = make_short4(l[4], l[5], l[6], l[7]);
    }
    __syncthreads();

    const float beta = betap[0];
    // ---- P5: T2 = relu(xcn @ xcn_w1 + b) : A -> B ----
    {
        f32x4 acc[2];
        layer_core(AH, AL, WFH + 3 * 65536, acc);
        const int col = (wq << 4) + fr;
        const float bb = bcn1[col];
        #pragma unroll
        for (int mf = 0; mf < 2; ++mf)
            #pragma unroll
            for (int r = 0; r < 4; ++r) {
                const int row = mf * 16 + q * 4 + r;
                float v = fmaxf(acc[mf][r] + bb, 0.f);
                short h, l;
                split2(v, h, l);
                const int cw = (((col >> 3) ^ (row & 7)) << 3) + (col & 7);
                BH[row][cw] = h;
                BL[row][cw] = l;
            }
    }
    __syncthreads();
    // ---- P6: z = relu(T2 @ xcn_w2 + b)*beta + XIJ(regs) : B -> A ----
    {
        f32x4 acc[2];
        layer_core(BH, BL, WFH + 4 * 65536, acc);
        const int col = (wq << 4) + fr;
        const float bb = bcn2[col];
        #pragma unroll
        for (int mf = 0; mf < 2; ++mf)
            #pragma unroll
            for (int r = 0; r < 4; ++r) {
                const int row = mf * 16 + q * 4 + r;
                float v = fmaxf(acc[mf][r] + bb, 0.f) * beta + xijr[mf][r];
                short h, l;
                split2(v, h, l);
                const int cw = (((col >> 3) ^ (row & 7)) << 3) + (col & 7);
                AH[row][cw] = h;
                AL[row][cw] = l;
            }
    }
    __syncthreads();
    // ---- P7: out = relu(z @ lin_w1 + b) @ w2 (gemv fused) ----
    {
        f32x4 acc[2];
        layer_core(AH, AL, WFH + 5 * 65536, acc);
        const int col = (wq << 4) + fr;
        const float bb = blin1[col];
        const float w2c = w2[col];
        #pragma unroll
        for (int mf = 0; mf < 2; ++mf) {
            #pragma unroll
            for (int r = 0; r < 4; ++r) {
                float s = fmaxf(acc[mf][r] + bb, 0.f) * w2c;
                s += __shfl_xor(s, 1); s += __shfl_xor(s, 2);
                s += __shfl_xor(s, 4); s += __shfl_xor(s, 8);
                if (fr == 0) atomicAdd(&out32[mf * 16 + q * 4 + r], s);
            }
        }
    }
    __syncthreads();
    if (t < 32) out[e0 + t] = out32[t] + b2o[0];
}

extern "C" void kernel_launch(void* const* d_in, const int* in_sizes, int n_in,
                              void* d_out, int out_size, void* d_ws, size_t ws_size,
                              hipStream_t stream) {
    const float* x       = (const float*)d_in[0];
    const float* adj     = (const float*)d_in[1];
    const int*   tar_ei  = (const int*)  d_in[2];
    const float* xlin_w1 = (const float*)d_in[3];
    const float* xlin_b1 = (const float*)d_in[4];
    const float* xlin_w2 = (const float*)d_in[5];
    const float* xlin_b2 = (const float*)d_in[6];
    const float* xcn_w1  = (const float*)d_in[7];
    const float* xcn_b1  = (const float*)d_in[8];
    const float* xcn_w2  = (const float*)d_in[9];
    const float* xcn_b2  = (const float*)d_in[10];
    const float* xij_w   = (const float*)d_in[11];
    const float* xij_b   = (const float*)d_in[12];
    const float* lin_w1  = (const float*)d_in[13];
    const float* lin_b1  = (const float*)d_in[14];
    const float* lin_w2  = (const float*)d_in[15];
    const float* lin_b2  = (const float*)d_in[16];
    const float* beta    = (const float*)d_in[17];
    float* out = (float*)d_out;

    char* ws = (char*)d_ws;
    const size_t MB = 1024 * 1024;
    unsigned long long* bits = (unsigned long long*)(ws);       // 8 MB
    short* WFH  = (short*)(ws +  8 * MB);   // 768 KB
    short* WFL  = (short*)(ws +  9 * MB);   // 768 KB

    WPtrs wp;
    wp.p[0] = xlin_w1; wp.p[1] = xlin_w2; wp.p[2] = xij_w;
    wp.p[3] = xcn_w1;  wp.p[4] = xcn_w2;  wp.p[5] = lin_w1;

    hipLaunchKernelGGL(k_prep, dim3(48 + 2048), dim3(256), 0, stream,
                       adj, bits, wp, WFH, WFL);
    hipLaunchKernelGGL(k_edge_mega, dim3(E_EDGES / 32), dim3(1024), 0, stream,
                       bits, x, tar_ei, WFH,
                       xlin_b1, xlin_b2, xij_b, xcn_b1, xcn_b2, lin_b1,
                       beta, lin_w2, lin_b2, out);
}